// Round 16
// baseline (259.360 us; speedup 1.0000x reference)
//
#include <hip/hip_runtime.h>
#include <hip/hip_fp16.h>

#define IN_CH 11
#define HID 64
#define PAD 64
#define OVCAP 16384
#define NBLK 512
#define BSH 7            // bucket = dst >> 7 (128 nodes/bucket)
#define NBKT 782         // ceil(100000/128)
#define CAP8 768         // per-(xcd,bucket) capacity: mean 512, +11 sigma
#define OVFLAG (1 << 30) // marks cell-overflow ov entries (written by build role)
#define NB2 32           // fuse2 nodes per block (grid 3125 -> fills the CUs)

typedef _Float16 half8_t __attribute__((ext_vector_type(8)));
typedef float f32x4_t __attribute__((ext_vector_type(4)));
typedef int i32x4_t __attribute__((ext_vector_type(4)));

// ---- k_pb: build role (blocks 0..NBLK-1) + prep role (rest).
__global__ __launch_bounds__(256) void k_pb(
        const float* __restrict__ x, const float* __restrict__ Wl2,
        const float* __restrict__ Wr2, const int* __restrict__ src,
        const int* __restrict__ dst, unsigned* __restrict__ xphu,
        __half* __restrict__ wl2h, __half* __restrict__ wr2h,
        unsigned* __restrict__ ebuf, int* __restrict__ bcnt8,
        int* __restrict__ ovcnt, int* __restrict__ ov,
        int E, int csz, int N) {
    __shared__ int h[NBKT];
    __shared__ int cur[NBKT];
    __shared__ int lim[NBKT];
    int tid = threadIdx.x, blk = blockIdx.x;
    if (blk >= NBLK) {
        // ---- prep role ----
        int i = (blk - NBLK) * 256 + tid;
        if (i < HID * HID) {
            wl2h[i] = __float2half_rn(Wl2[i]);
            wr2h[i] = __float2half_rn(Wr2[i]);
        }
        if (i < (N + 1) * 8) {               // one uint = 2 fp16 channels
            int n = i >> 3, j = (i & 7) * 2;
            float a = 0.f, b = 0.f;
            if (n < N) {
                if (j < IN_CH) a = x[n * IN_CH + j];
                if (j + 1 < IN_CH) b = x[n * IN_CH + j + 1];
            }
            unsigned lo = (unsigned)__half_as_ushort(__float2half_rn(a));
            unsigned hi = (unsigned)__half_as_ushort(__float2half_rn(b));
            xphu[i] = lo | (hi << 16);
        }
        return;
    }
    // ---- build role ----
    int xcd = blk & 7;
    for (int t = tid; t < NBKT; t += 256) h[t] = 0;
    __syncthreads();
    int c0 = blk * csz, c1 = min(c0 + csz, E);
    for (int base = c0; base < c1; base += 1024) {
        int d[4]; bool ok[4];
        #pragma unroll
        for (int k = 0; k < 4; k++) {
            int e = base + tid + k * 256;
            ok[k] = e < c1;
            d[k] = ok[k] ? dst[e] : 0;
        }
        #pragma unroll
        for (int k = 0; k < 4; k++)
            if (ok[k]) atomicAdd(&h[d[k] >> BSH], 1);
    }
    __syncthreads();
    for (int t = tid; t < NBKT; t += 256) {
        int hc = h[t];
        int cell = xcd * NBKT + t;
        int base = cell * CAP8;
        int off = (hc > 0) ? atomicAdd(&bcnt8[cell], hc) : 0;
        cur[t] = base + off;
        lim[t] = base + CAP8;
    }
    __syncthreads();
    for (int base = c0; base < c1; base += 1024) {
        int d[4], s[4], slot[4];
        bool ok[4];
        #pragma unroll
        for (int k = 0; k < 4; k++) {
            int e = base + tid + k * 256;
            ok[k] = e < c1;
            d[k] = ok[k] ? dst[e] : 0;
            s[k] = ok[k] ? __builtin_nontemporal_load(&src[e]) : 0;
        }
        #pragma unroll
        for (int k = 0; k < 4; k++)
            if (ok[k]) slot[k] = atomicAdd(&cur[d[k] >> BSH], 1);
        #pragma unroll
        for (int k = 0; k < 4; k++) {
            if (!ok[k]) continue;
            if (slot[k] < lim[d[k] >> BSH]) {
                ebuf[slot[k]] = ((unsigned)s[k] << 7) | (unsigned)(d[k] & 127);
            } else {
                int q = atomicAdd(ovcnt, 1);
                if (q < OVCAP) { ov[2 * q] = d[k] | OVFLAG; ov[2 * q + 1] = s[k]; }
            }
        }
    }
}

// ---- fuse1: 2 blocks per bucket. Each block scans the bucket's 8 segments
// and keeps only its 64-row half (disjoint ownership -> exact counts).
// LDS 19.7KB -> 4 resident blocks (wave-limited); grid 1564 = 6.1 blk/CU.
__global__ __launch_bounds__(512) void k_fuse1(
    const unsigned* __restrict__ ebuf, const int* __restrict__ bcnt8,
    const float* __restrict__ x, const unsigned* __restrict__ xphu,
    const float* __restrict__ Wl, const float* __restrict__ bl,
    const float* __restrict__ Wr,
    int* __restrict__ cnt, int* __restrict__ col64,
    int* __restrict__ ovcnt, int* __restrict__ ov,
    unsigned* __restrict__ h1h, int N) {
    __shared__ int lc[64];
    __shared__ int colsh[64 * PAD];      // 16 KB
    __shared__ float aggsh[64][12];      // 3 KB (IN_CH=11 real channels + 1)
    int tid = threadIdx.x;
    int bb = blockIdx.x >> 1, half = blockIdx.x & 1;
    int lo = (bb << BSH) + (half << 6);  // this block's 64-row base
    int hi = min(lo + 64, N);
    int nn = hi - lo; if (nn < 0) nn = 0;
    for (int i = tid; i < 64 * PAD / 4; i += 512) {
        i32x4_t fill = {N, N, N, N};
        ((i32x4_t*)colsh)[i] = fill;
    }
    if (tid < 64) lc[tid] = 0;
    for (int i = tid; i < 64 * 12; i += 512) ((float*)aggsh)[i] = 0.f;
    __syncthreads();
    // scan all 8 segments of bucket bb; keep rows whose (row>>6) == half
    int ccs[8];
    #pragma unroll
    for (int xc = 0; xc < 8; xc++)
        ccs[xc] = min(bcnt8[xc * NBKT + bb], CAP8);
    for (int i = tid; i < 8 * CAP8; i += 512) {
        int xc = i / CAP8;
        int idx = i - xc * CAP8;
        if (idx < ccs[xc]) {
            unsigned p = __builtin_nontemporal_load(
                &ebuf[(size_t)(xc * NBKT + bb) * CAP8 + idx]);
            int row7 = (int)(p & 127u);
            if ((row7 >> 6) == half) {
                int r = row7 & 63;
                int sv = (int)(p >> 7);
                int k = atomicAdd(&lc[r], 1);
                if (k < PAD) {
                    colsh[(r << 6) | ((k + r) & 63)] = sv;   // rotated slot
                } else {
                    int q = atomicAdd(ovcnt, 1);
                    if (q < OVCAP) { ov[2 * q] = lo + r; ov[2 * q + 1] = sv; }
                    for (int ch = 0; ch < IN_CH; ch++)       // layer-1 inline
                        atomicAdd(&aggsh[r][ch], x[sv * IN_CH + ch]);
                }
            }
        }
    }
    __syncthreads();
    // cell-overflow entries (flagged, written by build role, complete) layer 1
    {
        int c = *ovcnt; if (c > OVCAP) c = OVCAP;
        for (int i = tid; i < c; i += 512) {
            int d = ov[2 * i];
            if (d & OVFLAG) {
                int dd = d & ~OVFLAG;
                if (dd >= lo && dd < hi) {
                    int s = ov[2 * i + 1];
                    for (int ch = 0; ch < IN_CH; ch++)
                        atomicAdd(&aggsh[dd - lo][ch], x[s * IN_CH + ch]);
                }
            }
        }
    }
    // col64 + cnt writeout (regular stores: fuse2 reads benefit from L2)
    if (nn > 0) {
        i32x4_t* dst4 = (i32x4_t*)col64 + (size_t)lo * 16;
        for (int i = tid; i < nn * 16; i += 512) dst4[i] = ((i32x4_t*)colsh)[i];
        if (tid < nn) cnt[lo + tid] = lc[tid];
    }
    if (blockIdx.x == 0 && tid < 32) h1h[(size_t)N * 32 + tid] = 0u; // pad row
    __syncthreads();
    // agg1 phase: 8 rows per wave, 2 rows per iteration for MLP
    int lane = tid & 63, wv = tid >> 6;
    int c8 = lane & 7, sub = lane >> 3;
    for (int it = 0; it < 8; it += 2) {
        int rA = wv * 8 + it, rB = rA + 1;
        bool okA = rA < nn, okB = rB < nn;
        int sA[8], sB[8];
        #pragma unroll
        for (int jj = 0; jj < 8; jj++) {
            sA[jj] = okA ? colsh[(rA << 6) | (sub + 8 * jj)] : N;
            sB[jj] = okB ? colsh[(rB << 6) | (sub + 8 * jj)] : N;
        }
        unsigned vA[8], vB[8];
        #pragma unroll
        for (int jj = 0; jj < 8; jj++) vA[jj] = xphu[sA[jj] * 8 + c8];
        #pragma unroll
        for (int jj = 0; jj < 8; jj++) vB[jj] = xphu[sB[jj] * 8 + c8];
        __half2 aA = __floats2half2_rn(0.f, 0.f);
        __half2 aB = __floats2half2_rn(0.f, 0.f);
        #pragma unroll
        for (int jj = 0; jj < 8; jj++) {
            aA = __hadd2(aA, *(__half2*)&vA[jj]);
            aB = __hadd2(aB, *(__half2*)&vB[jj]);
        }
        float2 fA = __half22float2(aA);
        float2 fB = __half22float2(aB);
        #pragma unroll
        for (int off = 8; off <= 32; off <<= 1) {
            fA.x += __shfl_xor(fA.x, off);
            fA.y += __shfl_xor(fA.y, off);
            fB.x += __shfl_xor(fB.x, off);
            fB.y += __shfl_xor(fB.y, off);
        }
        // channels 2*lane, 2*lane+1; only lanes 0-5 carry real channels (0-11)
        if (lane < 6 && okA) {
            aggsh[rA][2 * lane]     += fA.x;
            aggsh[rA][2 * lane + 1] += fA.y;
        }
        if (lane < 6 && okB) {
            aggsh[rB][2 * lane]     += fB.x;
            aggsh[rB][2 * lane + 1] += fB.y;
        }
    }
    __syncthreads();
    // dense1 phase: 2 rows per iteration
    for (int it = 0; it < 8; it += 2) {
        int rA = wv * 8 + it, rB = rA + 1;
        bool okA = rA < nn, okB = rB < nn;
        int nA = lo + (okA ? rA : 0), nB = lo + (okB ? rB : 0);
        int degA = okA ? lc[rA] : 0, degB = okB ? lc[rB] : 0;
        float invA = degA > 0 ? 1.f / (float)degA : 0.f;
        float invB = degB > 0 ? 1.f / (float)degB : 0.f;
        float mvA = (okA && lane < 12) ? aggsh[rA][lane] * invA : 0.f;
        float mvB = (okB && lane < 12) ? aggsh[rB][lane] * invB : 0.f;
        float xvA = (lane < IN_CH) ? x[nA * IN_CH + lane] : 0.f;
        float xvB = (lane < IN_CH) ? x[nB * IN_CH + lane] : 0.f;
        float hA = bl[lane], hB = hA;
        #pragma unroll
        for (int c = 0; c < IN_CH; c++) {
            float wl = Wl[lane * IN_CH + c], wr = Wr[lane * IN_CH + c];
            hA += wl * __shfl(mvA, c) + wr * __shfl(xvA, c);
            hB += wl * __shfl(mvB, c) + wr * __shfl(xvB, c);
        }
        hA = fmaxf(hA, 0.f); hB = fmaxf(hB, 0.f);
        unsigned myA = (unsigned)__half_as_ushort(__float2half_rn(hA));
        unsigned myB = (unsigned)__half_as_ushort(__float2half_rn(hB));
        unsigned nxA = __shfl_down(myA, 1);
        unsigned nxB = __shfl_down(myB, 1);
        if ((lane & 1) == 0) {
            if (okA) h1h[nA * 32 + (lane >> 1)] = myA | (nxA << 16);
            if (okB) h1h[nB * 32 + (lane >> 1)] = myB | (nxB << 16);
        }
    }
}

// ---- fuse2 = agg2 + ov2 + dense2: 32 nodes/block, 256 threads (grid 3125
// fills the CUs; 20KB LDS -> 8 blocks/CU). fp16 means into LDS (XOR swizzle),
// MFMA with LDS-staged weights, out written directly.
__global__ __launch_bounds__(256) void k_fuse2(
    const uint4* __restrict__ h1h4, const int* __restrict__ col64,
    const int* __restrict__ cnt, const int* __restrict__ ovcnt,
    const int* __restrict__ ov,
    const __half* __restrict__ wl2h, const __half* __restrict__ wr2h,
    const float* __restrict__ bl, const float* __restrict__ Wlin,
    const float* __restrict__ blin, float* __restrict__ out, int N) {
    union U { uint4 u; half8_t h; };
    __shared__ uint4 meansh[NB2 * 8];    // 4 KB fp16 means, XOR-swizzled
    __shared__ uint4 wsh[2][64 * 8];     // 16 KB weights, XOR-swizzled
    int tid = threadIdx.x, b = blockIdx.x;
    int lo = b * NB2, hi = min(lo + NB2, N);
    int nn = hi - lo;
    int lane = tid & 63, wv = tid >> 6;  // 4 waves
    // stage weights (L2-hot) into LDS; swizzle pos q^(o&7)
    {
        const uint4* wlu = (const uint4*)wl2h;
        const uint4* wru = (const uint4*)wr2h;
        for (int i = tid; i < 64 * 8; i += 256) {
            int o = i >> 3, q = i & 7;
            wsh[0][(o << 3) | (q ^ (o & 7))] = wlu[i];
            wsh[1][(o << 3) | (q ^ (o & 7))] = wru[i];
        }
    }
    // phase A: per-node gather + fp16 mean -> LDS, 2 rows per iteration,
    // 8 rows per wave.
    int c8 = lane & 7, sub = lane >> 3;
    for (int it = 0; it < 8; it += 2) {
        int rA = wv * 8 + it, rB = rA + 1;
        bool okA = rA < nn, okB = rB < nn;
        int nA = lo + (okA ? rA : 0), nB = lo + (okB ? rB : 0);
        const int* cbA = col64 + (size_t)nA * PAD;
        const int* cbB = col64 + (size_t)nB * PAD;
        int sA[8], sB[8];
        #pragma unroll
        for (int jj = 0; jj < 8; jj++) {
            sA[jj] = okA ? __builtin_nontemporal_load(&cbA[sub + 8 * jj]) : N;
            sB[jj] = okB ? __builtin_nontemporal_load(&cbB[sub + 8 * jj]) : N;
        }
        uint4 vA[8], vB[8];
        #pragma unroll
        for (int jj = 0; jj < 8; jj++) vA[jj] = h1h4[(size_t)sA[jj] * 8 + c8];
        #pragma unroll
        for (int jj = 0; jj < 8; jj++) vB[jj] = h1h4[(size_t)sB[jj] * 8 + c8];
        __half2 aA[4], aB[4];
        #pragma unroll
        for (int t = 0; t < 4; t++) {
            aA[t] = __floats2half2_rn(0.f, 0.f);
            aB[t] = __floats2half2_rn(0.f, 0.f);
        }
        #pragma unroll
        for (int jj = 0; jj < 8; jj++) {
            aA[0] = __hadd2(aA[0], *(__half2*)&vA[jj].x);
            aA[1] = __hadd2(aA[1], *(__half2*)&vA[jj].y);
            aA[2] = __hadd2(aA[2], *(__half2*)&vA[jj].z);
            aA[3] = __hadd2(aA[3], *(__half2*)&vA[jj].w);
            aB[0] = __hadd2(aB[0], *(__half2*)&vB[jj].x);
            aB[1] = __hadd2(aB[1], *(__half2*)&vB[jj].y);
            aB[2] = __hadd2(aB[2], *(__half2*)&vB[jj].z);
            aB[3] = __hadd2(aB[3], *(__half2*)&vB[jj].w);
        }
        float accA[8], accB[8];
        #pragma unroll
        for (int t = 0; t < 4; t++) {
            float2 fA = __half22float2(aA[t]);
            float2 fB = __half22float2(aB[t]);
            accA[2 * t] = fA.x; accA[2 * t + 1] = fA.y;
            accB[2 * t] = fB.x; accB[2 * t + 1] = fB.y;
        }
        #pragma unroll
        for (int off = 8; off <= 32; off <<= 1) {
            #pragma unroll
            for (int t = 0; t < 8; t++) {
                accA[t] += __shfl_xor(accA[t], off);
                accB[t] += __shfl_xor(accB[t], off);
            }
        }
        if (sub == 0) {
            if (okA) {
                int deg = cnt[nA];
                float inv = deg > 0 ? 1.f / (float)deg : 0.f;
                __half2 h0 = __floats2half2_rn(accA[0] * inv, accA[1] * inv);
                __half2 h1 = __floats2half2_rn(accA[2] * inv, accA[3] * inv);
                __half2 h2 = __floats2half2_rn(accA[4] * inv, accA[5] * inv);
                __half2 h3 = __floats2half2_rn(accA[6] * inv, accA[7] * inv);
                uint4 o;
                o.x = *(unsigned*)&h0; o.y = *(unsigned*)&h1;
                o.z = *(unsigned*)&h2; o.w = *(unsigned*)&h3;
                meansh[(rA << 3) | (c8 ^ (rA & 7))] = o;
            }
            if (okB) {
                int deg = cnt[nB];
                float inv = deg > 0 ? 1.f / (float)deg : 0.f;
                __half2 h0 = __floats2half2_rn(accB[0] * inv, accB[1] * inv);
                __half2 h1 = __floats2half2_rn(accB[2] * inv, accB[3] * inv);
                __half2 h2 = __floats2half2_rn(accB[4] * inv, accB[5] * inv);
                __half2 h3 = __floats2half2_rn(accB[6] * inv, accB[7] * inv);
                uint4 o;
                o.x = *(unsigned*)&h0; o.y = *(unsigned*)&h1;
                o.z = *(unsigned*)&h2; o.w = *(unsigned*)&h3;
                meansh[(rB << 3) | (c8 ^ (rB & 7))] = o;
            }
        }
    }
    __syncthreads();
    // phase B: overflow contributions (statistically empty; serial is fine)
    if (tid == 0) {
        int c = *ovcnt; if (c > OVCAP) c = OVCAP;
        for (int i = 0; i < c; i++) {
            int d = ov[2 * i] & ~OVFLAG;
            if (d >= lo && d < hi && (ov[2 * i] != 0)) {
                int s = ov[2 * i + 1];
                int row = d - lo;
                int deg = cnt[d];
                float inv = deg > 0 ? 1.f / (float)deg : 0.f;
                for (int q = 0; q < 8; q++) {
                    uint4* mp = &meansh[(row << 3) | (q ^ (row & 7))];
                    uint4 m = *mp;
                    uint4 hh = h1h4[(size_t)s * 8 + q];
                    __half2* m2 = (__half2*)&m;
                    __half2* h2v = (__half2*)&hh;
                    for (int k = 0; k < 4; k++) {
                        float2 fm = __half22float2(m2[k]);
                        float2 fh = __half22float2(h2v[k]);
                        m2[k] = __floats2half2_rn(fm.x + fh.x * inv, fm.y + fh.y * inv);
                    }
                    *mp = m;
                }
            }
        }
    }
    __syncthreads();
    // phase C: dense2 MFMA; waves 0,1 each handle one 16-node tile
    int r16 = lane & 15, quad = lane >> 4;
    int rb = wv * 16;
    if (wv < 2 && rb < nn) {
        float bl_c[4], wl_c[4];
        #pragma unroll
        for (int tt = 0; tt < 4; tt++) {
            bl_c[tt] = bl[tt * 16 + r16];
            wl_c[tt] = Wlin[tt * 16 + r16];
        }
        float b0 = blin[0];
        int row = rb + r16; if (row >= nn) row = nn - 1;
        int n = lo + row;
        U a0, a1, a2, a3;
        a0.u = meansh[(row << 3) | (quad ^ (row & 7))];
        a1.u = meansh[(row << 3) | ((4 + quad) ^ (row & 7))];
        a2.u = h1h4[(size_t)n * 8 + quad];
        a3.u = h1h4[(size_t)n * 8 + 4 + quad];
        float p0 = 0.f, p1 = 0.f, p2 = 0.f, p3 = 0.f;
        #pragma unroll
        for (int tt = 0; tt < 4; tt++) {
            int o = tt * 16 + r16;
            U b0u, b1u, b2u, b3u;
            b0u.u = wsh[0][(o << 3) | (quad ^ (o & 7))];
            b1u.u = wsh[0][(o << 3) | ((4 + quad) ^ (o & 7))];
            b2u.u = wsh[1][(o << 3) | (quad ^ (o & 7))];
            b3u.u = wsh[1][(o << 3) | ((4 + quad) ^ (o & 7))];
            f32x4_t c = {0.f, 0.f, 0.f, 0.f};
            c = __builtin_amdgcn_mfma_f32_16x16x32_f16(a0.h, b0u.h, c, 0, 0, 0);
            c = __builtin_amdgcn_mfma_f32_16x16x32_f16(a1.h, b1u.h, c, 0, 0, 0);
            c = __builtin_amdgcn_mfma_f32_16x16x32_f16(a2.h, b2u.h, c, 0, 0, 0);
            c = __builtin_amdgcn_mfma_f32_16x16x32_f16(a3.h, b3u.h, c, 0, 0, 0);
            p0 += fmaxf(c[0] + bl_c[tt], 0.f) * wl_c[tt];
            p1 += fmaxf(c[1] + bl_c[tt], 0.f) * wl_c[tt];
            p2 += fmaxf(c[2] + bl_c[tt], 0.f) * wl_c[tt];
            p3 += fmaxf(c[3] + bl_c[tt], 0.f) * wl_c[tt];
        }
        #pragma unroll
        for (int off = 1; off <= 8; off <<= 1) {
            p0 += __shfl_xor(p0, off); p1 += __shfl_xor(p1, off);
            p2 += __shfl_xor(p2, off); p3 += __shfl_xor(p3, off);
        }
        if (r16 == 0) {
            int nn2 = lo + rb + quad * 4;
            if (nn2 + 3 < N) {
                ((float4*)out)[nn2 >> 2] = make_float4(p0 + b0, p1 + b0, p2 + b0, p3 + b0);
            } else {
                if (nn2 + 0 < N) out[nn2 + 0] = p0 + b0;
                if (nn2 + 1 < N) out[nn2 + 1] = p1 + b0;
                if (nn2 + 2 < N) out[nn2 + 2] = p2 + b0;
                if (nn2 + 3 < N) out[nn2 + 3] = p3 + b0;
            }
        }
    }
}

// ---------------- launch ----------------

extern "C" void kernel_launch(void* const* d_in, const int* in_sizes, int n_in,
                              void* d_out, int out_size, void* d_ws, size_t ws_size,
                              hipStream_t stream) {
    const float* x    = (const float*)d_in[0];
    const int*   ei   = (const int*)d_in[1];
    const float* Wl1  = (const float*)d_in[2];
    const float* bl1  = (const float*)d_in[3];
    const float* Wr1  = (const float*)d_in[4];
    const float* Wl2  = (const float*)d_in[5];
    const float* bl2  = (const float*)d_in[6];
    const float* Wr2  = (const float*)d_in[7];
    const float* Wlin = (const float*)d_in[8];
    const float* blin = (const float*)d_in[9];
    float* out = (float*)d_out;

    int N = in_sizes[0] / IN_CH;   // 100000
    int E = in_sizes[1] / 2;       // 3200000
    const int* srcp = ei;
    const int* dstp = ei + E;

    // workspace (int offsets):
    //  cnt   @ 0          (N+1)
    //  col64 @ 100,032    (6.4M; fuse1->fuse2)
    //  xph   @ 6,500,032  ((N+1)*8; pb->fuse1)
    //  ebuf  @ 7,300,064  (8*782*768 = 4,804,608; pb->fuse1)
    //  bcnt8 @ 12,104,672 (6,256; pb->fuse1)
    //  h1h   @ 12,900,096 ((N+1)*32; fuse1->fuse2)
    //  ov    @ 16,100,128 (2*OVCAP)
    //  wl2h  @ 16,132,896 / wr2h @ 16,134,944 (2048 each)
    int* ws       = (int*)d_ws;
    int* cnt      = ws;
    int* ovcnt    = ws + N;
    int* col64    = ws + 100032;
    unsigned* xph = (unsigned*)(ws + 6500032);
    unsigned* ebuf= (unsigned*)(ws + 7300064);
    int* bcnt8    = ws + 12104672;
    unsigned* h1h = (unsigned*)(ws + 12900096);
    int* ov       = ws + 16100128;
    __half* wl2h  = (__half*)(ws + 16132896);
    __half* wr2h  = (__half*)(ws + 16134944);

    int csz = (E + NBLK - 1) / NBLK;                  // 6250
    int nprep = ((N + 1) * 8 + 255) / 256;            // 3126

    hipMemsetAsync(bcnt8, 0, 8 * NBKT * sizeof(int), stream);
    hipMemsetAsync(ovcnt, 0, sizeof(int), stream);
    hipMemsetAsync(ov, 0, 2 * OVCAP * sizeof(int), stream);

    k_pb    <<<NBLK + nprep, 256, 0, stream>>>(x, Wl2, Wr2, srcp, dstp, xph,
                                               wl2h, wr2h, ebuf, bcnt8,
                                               ovcnt, ov, E, csz, N);
    k_fuse1 <<<2 * NBKT, 512, 0, stream>>>(ebuf, bcnt8, x, xph, Wl1, bl1, Wr1,
                                           cnt, col64, ovcnt, ov, h1h, N);
    k_fuse2 <<<(N + NB2 - 1) / NB2, 256, 0, stream>>>((const uint4*)h1h, col64,
                                       cnt, ovcnt, ov,
                                       wl2h, wr2h, bl2, Wlin, blin, out, N);
}

// Round 18
// 239.108 us; speedup vs baseline: 1.0847x; 1.0847x over previous
//
#include <hip/hip_runtime.h>
#include <hip/hip_fp16.h>

#define IN_CH 11
#define HID 64
#define PAD 64
#define OVCAP 16256
#define NBLK 512
#define BSH 7            // bucket = dst >> 7 (128 nodes/bucket)
#define NBKT 782         // ceil(100000/128)
#define CAP8 768         // per-(xcd,bucket) capacity: mean 512, +11 sigma
#define OVFLAG (1 << 30) // marks cell-overflow ov entries (written by build role)
#define NB2 32           // fuse2 nodes per block (grid 3125 -> fills the CUs)

typedef _Float16 half8_t __attribute__((ext_vector_type(8)));
typedef float f32x4_t __attribute__((ext_vector_type(4)));
typedef int i32x4_t __attribute__((ext_vector_type(4)));

// ---- k_pb: build role (blocks 0..NBLK-1) + prep role (rest).
__global__ __launch_bounds__(256) void k_pb(
        const float* __restrict__ x, const float* __restrict__ Wl2,
        const float* __restrict__ Wr2, const int* __restrict__ src,
        const int* __restrict__ dst, unsigned* __restrict__ xphu,
        __half* __restrict__ wl2h, __half* __restrict__ wr2h,
        unsigned* __restrict__ ebuf, int* __restrict__ bcnt8,
        int* __restrict__ ovcnt, int* __restrict__ ov,
        int E, int csz, int N) {
    __shared__ int h[NBKT];
    __shared__ int cur[NBKT];
    __shared__ int lim[NBKT];
    int tid = threadIdx.x, blk = blockIdx.x;
    if (blk >= NBLK) {
        // ---- prep role ----
        int i = (blk - NBLK) * 256 + tid;
        if (i < HID * HID) {
            wl2h[i] = __float2half_rn(Wl2[i]);
            wr2h[i] = __float2half_rn(Wr2[i]);
        }
        if (i < (N + 1) * 8) {               // one uint = 2 fp16 channels
            int n = i >> 3, j = (i & 7) * 2;
            float a = 0.f, b = 0.f;
            if (n < N) {
                if (j < IN_CH) a = x[n * IN_CH + j];
                if (j + 1 < IN_CH) b = x[n * IN_CH + j + 1];
            }
            unsigned lo = (unsigned)__half_as_ushort(__float2half_rn(a));
            unsigned hi = (unsigned)__half_as_ushort(__float2half_rn(b));
            xphu[i] = lo | (hi << 16);
        }
        return;
    }
    // ---- build role ----
    int xcd = blk & 7;
    for (int t = tid; t < NBKT; t += 256) h[t] = 0;
    __syncthreads();
    int c0 = blk * csz, c1 = min(c0 + csz, E);
    for (int base = c0; base < c1; base += 1024) {
        int d[4]; bool ok[4];
        #pragma unroll
        for (int k = 0; k < 4; k++) {
            int e = base + tid + k * 256;
            ok[k] = e < c1;
            d[k] = ok[k] ? dst[e] : 0;
        }
        #pragma unroll
        for (int k = 0; k < 4; k++)
            if (ok[k]) atomicAdd(&h[d[k] >> BSH], 1);
    }
    __syncthreads();
    for (int t = tid; t < NBKT; t += 256) {
        int hc = h[t];
        int cell = xcd * NBKT + t;
        int base = cell * CAP8;
        int off = (hc > 0) ? atomicAdd(&bcnt8[cell], hc) : 0;
        cur[t] = base + off;
        lim[t] = base + CAP8;
    }
    __syncthreads();
    for (int base = c0; base < c1; base += 1024) {
        int d[4], s[4], slot[4];
        bool ok[4];
        #pragma unroll
        for (int k = 0; k < 4; k++) {
            int e = base + tid + k * 256;
            ok[k] = e < c1;
            d[k] = ok[k] ? dst[e] : 0;
            s[k] = ok[k] ? __builtin_nontemporal_load(&src[e]) : 0;
        }
        #pragma unroll
        for (int k = 0; k < 4; k++)
            if (ok[k]) slot[k] = atomicAdd(&cur[d[k] >> BSH], 1);
        #pragma unroll
        for (int k = 0; k < 4; k++) {
            if (!ok[k]) continue;
            if (slot[k] < lim[d[k] >> BSH]) {
                ebuf[slot[k]] = ((unsigned)s[k] << 7) | (unsigned)(d[k] & 127);
            } else {
                int q = atomicAdd(ovcnt, 1);
                if (q < OVCAP) { ov[2 * q] = d[k] | OVFLAG; ov[2 * q + 1] = s[k]; }
            }
        }
    }
}

// ---- fuse1 = bbuild + agg1 + ov1 + dense1: col image in LDS (rotated rows to
// kill write bank conflicts), layer-1 aggregate from LDS, dense -> h1h.
__global__ __launch_bounds__(512) void k_fuse1(
    const unsigned* __restrict__ ebuf, const int* __restrict__ bcnt8,
    const float* __restrict__ x, const unsigned* __restrict__ xphu,
    const float* __restrict__ Wl, const float* __restrict__ bl,
    const float* __restrict__ Wr,
    int* __restrict__ cnt, int* __restrict__ col64,
    int* __restrict__ ovcnt, int* __restrict__ ov,
    unsigned* __restrict__ h1h, int N) {
    __shared__ int lc[128];
    __shared__ int colsh[128 * PAD];     // 32 KB
    __shared__ float aggsh[128][12];     // 6 KB (IN_CH=11 real channels + 1)
    int tid = threadIdx.x, b = blockIdx.x;
    int lo = b << BSH, hi = min(lo + 128, N);
    int nn = hi - lo;
    for (int i = tid; i < 128 * PAD / 4; i += 512) {
        i32x4_t fill = {N, N, N, N};
        ((i32x4_t*)colsh)[i] = fill;
    }
    if (tid < 128) lc[tid] = 0;
    for (int i = tid; i < 128 * 12; i += 512) ((float*)aggsh)[i] = 0.f;
    __syncthreads();
    // build col image: flat loop over all 8 segments, prefetched bounds -> MLP
    int ccs[8];
    #pragma unroll
    for (int xc = 0; xc < 8; xc++)
        ccs[xc] = min(bcnt8[xc * NBKT + b], CAP8);
    for (int i = tid; i < 8 * CAP8; i += 512) {
        int xc = i / CAP8;
        int idx = i - xc * CAP8;
        if (idx < ccs[xc]) {
            unsigned p = __builtin_nontemporal_load(
                &ebuf[(size_t)(xc * NBKT + b) * CAP8 + idx]);
            int row = (int)(p & 127u);
            int sv  = (int)(p >> 7);
            int r = atomicAdd(&lc[row], 1);
            if (r < PAD) {
                colsh[(row << 6) | ((r + row) & 63)] = sv;   // rotated slot
            } else {
                int q = atomicAdd(ovcnt, 1);
                if (q < OVCAP) { ov[2 * q] = lo + row; ov[2 * q + 1] = sv; }
                for (int ch = 0; ch < IN_CH; ch++)           // layer-1 inline
                    atomicAdd(&aggsh[row][ch], x[sv * IN_CH + ch]);
            }
        }
    }
    __syncthreads();
    // cell-overflow entries (flagged, written by build role, complete) layer 1
    {
        int c = *ovcnt; if (c > OVCAP) c = OVCAP;
        for (int i = tid; i < c; i += 512) {
            int d = ov[2 * i];
            if (d & OVFLAG) {
                int dd = d & ~OVFLAG;
                if (dd >= lo && dd < hi) {
                    int s = ov[2 * i + 1];
                    for (int ch = 0; ch < IN_CH; ch++)
                        atomicAdd(&aggsh[dd - lo][ch], x[s * IN_CH + ch]);
                }
            }
        }
    }
    // col64 + cnt writeout (regular stores: fuse2 reads benefit from L2)
    {
        i32x4_t* dst4 = (i32x4_t*)col64 + (size_t)lo * 16;
        for (int i = tid; i < nn * 16; i += 512) dst4[i] = ((i32x4_t*)colsh)[i];
        if (tid < nn) cnt[lo + tid] = lc[tid];
        if (b == 0 && tid < 32) h1h[(size_t)N * 32 + tid] = 0u;   // pad row
    }
    __syncthreads();
    // agg1 phase: 2 rows per iteration for MLP; reads all 64 slots per row
    int lane = tid & 63, wv = tid >> 6;
    int c8 = lane & 7, sub = lane >> 3;
    for (int it = 0; it < 16; it += 2) {
        int rA = wv * 16 + it, rB = rA + 1;
        bool okA = rA < nn, okB = rB < nn;
        int sA[8], sB[8];
        #pragma unroll
        for (int jj = 0; jj < 8; jj++) {
            sA[jj] = okA ? colsh[(rA << 6) | (sub + 8 * jj)] : N;
            sB[jj] = okB ? colsh[(rB << 6) | (sub + 8 * jj)] : N;
        }
        unsigned vA[8], vB[8];
        #pragma unroll
        for (int jj = 0; jj < 8; jj++) vA[jj] = xphu[sA[jj] * 8 + c8];
        #pragma unroll
        for (int jj = 0; jj < 8; jj++) vB[jj] = xphu[sB[jj] * 8 + c8];
        __half2 aA = __floats2half2_rn(0.f, 0.f);
        __half2 aB = __floats2half2_rn(0.f, 0.f);
        #pragma unroll
        for (int jj = 0; jj < 8; jj++) {
            aA = __hadd2(aA, *(__half2*)&vA[jj]);
            aB = __hadd2(aB, *(__half2*)&vB[jj]);
        }
        float2 fA = __half22float2(aA);
        float2 fB = __half22float2(aB);
        #pragma unroll
        for (int off = 8; off <= 32; off <<= 1) {
            fA.x += __shfl_xor(fA.x, off);
            fA.y += __shfl_xor(fA.y, off);
            fB.x += __shfl_xor(fB.x, off);
            fB.y += __shfl_xor(fB.y, off);
        }
        // channels 2*lane, 2*lane+1; only lanes 0-5 carry real channels (0-11)
        if (lane < 6 && okA) {
            aggsh[rA][2 * lane]     += fA.x;
            aggsh[rA][2 * lane + 1] += fA.y;
        }
        if (lane < 6 && okB) {
            aggsh[rB][2 * lane]     += fB.x;
            aggsh[rB][2 * lane + 1] += fB.y;
        }
    }
    __syncthreads();
    // dense1 phase: 2 rows per iteration
    for (int it = 0; it < 16; it += 2) {
        int rA = wv * 16 + it, rB = rA + 1;
        bool okA = rA < nn, okB = rB < nn;
        int nA = lo + (okA ? rA : 0), nB = lo + (okB ? rB : 0);
        int degA = okA ? lc[rA] : 0, degB = okB ? lc[rB] : 0;
        float invA = degA > 0 ? 1.f / (float)degA : 0.f;
        float invB = degB > 0 ? 1.f / (float)degB : 0.f;
        float mvA = (okA && lane < 12) ? aggsh[rA][lane] * invA : 0.f;
        float mvB = (okB && lane < 12) ? aggsh[rB][lane] * invB : 0.f;
        float xvA = (lane < IN_CH) ? x[nA * IN_CH + lane] : 0.f;
        float xvB = (lane < IN_CH) ? x[nB * IN_CH + lane] : 0.f;
        float hA = bl[lane], hB = hA;
        #pragma unroll
        for (int c = 0; c < IN_CH; c++) {
            float wl = Wl[lane * IN_CH + c], wr = Wr[lane * IN_CH + c];
            hA += wl * __shfl(mvA, c) + wr * __shfl(xvA, c);
            hB += wl * __shfl(mvB, c) + wr * __shfl(xvB, c);
        }
        hA = fmaxf(hA, 0.f); hB = fmaxf(hB, 0.f);
        unsigned myA = (unsigned)__half_as_ushort(__float2half_rn(hA));
        unsigned myB = (unsigned)__half_as_ushort(__float2half_rn(hB));
        unsigned nxA = __shfl_down(myA, 1);
        unsigned nxB = __shfl_down(myB, 1);
        if ((lane & 1) == 0) {
            if (okA) h1h[nA * 32 + (lane >> 1)] = myA | (nxA << 16);
            if (okB) h1h[nB * 32 + (lane >> 1)] = myB | (nxB << 16);
        }
    }
}

// ---- fuse2 = agg2 + ov2 + dense2: 32 nodes/block, 256 threads (grid 3125
// fills the CUs; 20KB LDS -> 8 blocks/CU). fp16 means into LDS (XOR swizzle),
// MFMA with LDS-staged weights, out written directly.
__global__ __launch_bounds__(256) void k_fuse2(
    const uint4* __restrict__ h1h4, const int* __restrict__ col64,
    const int* __restrict__ cnt, const int* __restrict__ ovcnt,
    const int* __restrict__ ov,
    const __half* __restrict__ wl2h, const __half* __restrict__ wr2h,
    const float* __restrict__ bl, const float* __restrict__ Wlin,
    const float* __restrict__ blin, float* __restrict__ out, int N) {
    union U { uint4 u; half8_t h; };
    __shared__ uint4 meansh[NB2 * 8];    // 4 KB fp16 means, XOR-swizzled
    __shared__ uint4 wsh[2][64 * 8];     // 16 KB weights, XOR-swizzled
    int tid = threadIdx.x, b = blockIdx.x;
    int lo = b * NB2, hi = min(lo + NB2, N);
    int nn = hi - lo;
    int lane = tid & 63, wv = tid >> 6;  // 4 waves
    // stage weights (L2-hot) into LDS; swizzle pos q^(o&7)
    {
        const uint4* wlu = (const uint4*)wl2h;
        const uint4* wru = (const uint4*)wr2h;
        for (int i = tid; i < 64 * 8; i += 256) {
            int o = i >> 3, q = i & 7;
            wsh[0][(o << 3) | (q ^ (o & 7))] = wlu[i];
            wsh[1][(o << 3) | (q ^ (o & 7))] = wru[i];
        }
    }
    // phase A: per-node gather + fp16 mean -> LDS, 2 rows per iteration,
    // 8 rows per wave.
    int c8 = lane & 7, sub = lane >> 3;
    for (int it = 0; it < 8; it += 2) {
        int rA = wv * 8 + it, rB = rA + 1;
        bool okA = rA < nn, okB = rB < nn;
        int nA = lo + (okA ? rA : 0), nB = lo + (okB ? rB : 0);
        const int* cbA = col64 + (size_t)nA * PAD;
        const int* cbB = col64 + (size_t)nB * PAD;
        int sA[8], sB[8];
        #pragma unroll
        for (int jj = 0; jj < 8; jj++) {
            sA[jj] = okA ? __builtin_nontemporal_load(&cbA[sub + 8 * jj]) : N;
            sB[jj] = okB ? __builtin_nontemporal_load(&cbB[sub + 8 * jj]) : N;
        }
        uint4 vA[8], vB[8];
        #pragma unroll
        for (int jj = 0; jj < 8; jj++) vA[jj] = h1h4[(size_t)sA[jj] * 8 + c8];
        #pragma unroll
        for (int jj = 0; jj < 8; jj++) vB[jj] = h1h4[(size_t)sB[jj] * 8 + c8];
        __half2 aA[4], aB[4];
        #pragma unroll
        for (int t = 0; t < 4; t++) {
            aA[t] = __floats2half2_rn(0.f, 0.f);
            aB[t] = __floats2half2_rn(0.f, 0.f);
        }
        #pragma unroll
        for (int jj = 0; jj < 8; jj++) {
            aA[0] = __hadd2(aA[0], *(__half2*)&vA[jj].x);
            aA[1] = __hadd2(aA[1], *(__half2*)&vA[jj].y);
            aA[2] = __hadd2(aA[2], *(__half2*)&vA[jj].z);
            aA[3] = __hadd2(aA[3], *(__half2*)&vA[jj].w);
            aB[0] = __hadd2(aB[0], *(__half2*)&vB[jj].x);
            aB[1] = __hadd2(aB[1], *(__half2*)&vB[jj].y);
            aB[2] = __hadd2(aB[2], *(__half2*)&vB[jj].z);
            aB[3] = __hadd2(aB[3], *(__half2*)&vB[jj].w);
        }
        float accA[8], accB[8];
        #pragma unroll
        for (int t = 0; t < 4; t++) {
            float2 fA = __half22float2(aA[t]);
            float2 fB = __half22float2(aB[t]);
            accA[2 * t] = fA.x; accA[2 * t + 1] = fA.y;
            accB[2 * t] = fB.x; accB[2 * t + 1] = fB.y;
        }
        #pragma unroll
        for (int off = 8; off <= 32; off <<= 1) {
            #pragma unroll
            for (int t = 0; t < 8; t++) {
                accA[t] += __shfl_xor(accA[t], off);
                accB[t] += __shfl_xor(accB[t], off);
            }
        }
        if (sub == 0) {
            if (okA) {
                int deg = cnt[nA];
                float inv = deg > 0 ? 1.f / (float)deg : 0.f;
                __half2 h0 = __floats2half2_rn(accA[0] * inv, accA[1] * inv);
                __half2 h1 = __floats2half2_rn(accA[2] * inv, accA[3] * inv);
                __half2 h2 = __floats2half2_rn(accA[4] * inv, accA[5] * inv);
                __half2 h3 = __floats2half2_rn(accA[6] * inv, accA[7] * inv);
                uint4 o;
                o.x = *(unsigned*)&h0; o.y = *(unsigned*)&h1;
                o.z = *(unsigned*)&h2; o.w = *(unsigned*)&h3;
                meansh[(rA << 3) | (c8 ^ (rA & 7))] = o;
            }
            if (okB) {
                int deg = cnt[nB];
                float inv = deg > 0 ? 1.f / (float)deg : 0.f;
                __half2 h0 = __floats2half2_rn(accB[0] * inv, accB[1] * inv);
                __half2 h1 = __floats2half2_rn(accB[2] * inv, accB[3] * inv);
                __half2 h2 = __floats2half2_rn(accB[4] * inv, accB[5] * inv);
                __half2 h3 = __floats2half2_rn(accB[6] * inv, accB[7] * inv);
                uint4 o;
                o.x = *(unsigned*)&h0; o.y = *(unsigned*)&h1;
                o.z = *(unsigned*)&h2; o.w = *(unsigned*)&h3;
                meansh[(rB << 3) | (c8 ^ (rB & 7))] = o;
            }
        }
    }
    __syncthreads();
    // phase B: overflow contributions (statistically empty; serial is fine)
    if (tid == 0) {
        int c = *ovcnt; if (c > OVCAP) c = OVCAP;
        for (int i = 0; i < c; i++) {
            int d = ov[2 * i] & ~OVFLAG;
            if (d >= lo && d < hi && (ov[2 * i] != 0)) {
                int s = ov[2 * i + 1];
                int row = d - lo;
                int deg = cnt[d];
                float inv = deg > 0 ? 1.f / (float)deg : 0.f;
                for (int q = 0; q < 8; q++) {
                    uint4* mp = &meansh[(row << 3) | (q ^ (row & 7))];
                    uint4 m = *mp;
                    uint4 hh = h1h4[(size_t)s * 8 + q];
                    __half2* m2 = (__half2*)&m;
                    __half2* h2v = (__half2*)&hh;
                    for (int k = 0; k < 4; k++) {
                        float2 fm = __half22float2(m2[k]);
                        float2 fh = __half22float2(h2v[k]);
                        m2[k] = __floats2half2_rn(fm.x + fh.x * inv, fm.y + fh.y * inv);
                    }
                    *mp = m;
                }
            }
        }
    }
    __syncthreads();
    // phase C: dense2 MFMA; waves 0,1 each handle one 16-node tile
    int r16 = lane & 15, quad = lane >> 4;
    int rb = wv * 16;
    if (wv < 2 && rb < nn) {
        float bl_c[4], wl_c[4];
        #pragma unroll
        for (int tt = 0; tt < 4; tt++) {
            bl_c[tt] = bl[tt * 16 + r16];
            wl_c[tt] = Wlin[tt * 16 + r16];
        }
        float b0 = blin[0];
        int row = rb + r16; if (row >= nn) row = nn - 1;
        int n = lo + row;
        U a0, a1, a2, a3;
        a0.u = meansh[(row << 3) | (quad ^ (row & 7))];
        a1.u = meansh[(row << 3) | ((4 + quad) ^ (row & 7))];
        a2.u = h1h4[(size_t)n * 8 + quad];
        a3.u = h1h4[(size_t)n * 8 + 4 + quad];
        float p0 = 0.f, p1 = 0.f, p2 = 0.f, p3 = 0.f;
        #pragma unroll
        for (int tt = 0; tt < 4; tt++) {
            int o = tt * 16 + r16;
            U b0u, b1u, b2u, b3u;
            b0u.u = wsh[0][(o << 3) | (quad ^ (o & 7))];
            b1u.u = wsh[0][(o << 3) | ((4 + quad) ^ (o & 7))];
            b2u.u = wsh[1][(o << 3) | (quad ^ (o & 7))];
            b3u.u = wsh[1][(o << 3) | ((4 + quad) ^ (o & 7))];
            f32x4_t c = {0.f, 0.f, 0.f, 0.f};
            c = __builtin_amdgcn_mfma_f32_16x16x32_f16(a0.h, b0u.h, c, 0, 0, 0);
            c = __builtin_amdgcn_mfma_f32_16x16x32_f16(a1.h, b1u.h, c, 0, 0, 0);
            c = __builtin_amdgcn_mfma_f32_16x16x32_f16(a2.h, b2u.h, c, 0, 0, 0);
            c = __builtin_amdgcn_mfma_f32_16x16x32_f16(a3.h, b3u.h, c, 0, 0, 0);
            p0 += fmaxf(c[0] + bl_c[tt], 0.f) * wl_c[tt];
            p1 += fmaxf(c[1] + bl_c[tt], 0.f) * wl_c[tt];
            p2 += fmaxf(c[2] + bl_c[tt], 0.f) * wl_c[tt];
            p3 += fmaxf(c[3] + bl_c[tt], 0.f) * wl_c[tt];
        }
        #pragma unroll
        for (int off = 1; off <= 8; off <<= 1) {
            p0 += __shfl_xor(p0, off); p1 += __shfl_xor(p1, off);
            p2 += __shfl_xor(p2, off); p3 += __shfl_xor(p3, off);
        }
        if (r16 == 0) {
            int nn2 = lo + rb + quad * 4;
            if (nn2 + 3 < N) {
                ((float4*)out)[nn2 >> 2] = make_float4(p0 + b0, p1 + b0, p2 + b0, p3 + b0);
            } else {
                if (nn2 + 0 < N) out[nn2 + 0] = p0 + b0;
                if (nn2 + 1 < N) out[nn2 + 1] = p1 + b0;
                if (nn2 + 2 < N) out[nn2 + 2] = p2 + b0;
                if (nn2 + 3 < N) out[nn2 + 3] = p3 + b0;
            }
        }
    }
}

// ---------------- launch ----------------

extern "C" void kernel_launch(void* const* d_in, const int* in_sizes, int n_in,
                              void* d_out, int out_size, void* d_ws, size_t ws_size,
                              hipStream_t stream) {
    const float* x    = (const float*)d_in[0];
    const int*   ei   = (const int*)d_in[1];
    const float* Wl1  = (const float*)d_in[2];
    const float* bl1  = (const float*)d_in[3];
    const float* Wr1  = (const float*)d_in[4];
    const float* Wl2  = (const float*)d_in[5];
    const float* bl2  = (const float*)d_in[6];
    const float* Wr2  = (const float*)d_in[7];
    const float* Wlin = (const float*)d_in[8];
    const float* blin = (const float*)d_in[9];
    float* out = (float*)d_out;

    int N = in_sizes[0] / IN_CH;   // 100000
    int E = in_sizes[1] / 2;       // 3200000
    const int* srcp = ei;
    const int* dstp = ei + E;

    // workspace (int offsets; max use 16,138,898 ints < 16,139,040 budget):
    //  cnt   @ 0          (N)
    //  col64 @ 100,032    (6.4M; fuse1->fuse2)
    //  xph   @ 6,500,032  ((N+1)*8; pb->fuse1)
    //  ebuf  @ 7,300,064  (8*782*768 = 4,804,608; pb->fuse1) end 12,104,672
    //  wl2h  @ 12,200,000 (2048 ints = 4096 halfs)
    //  wr2h  @ 12,202,048 (2048 ints)  [end 12,204,096 < h1h start]
    //  h1h   @ 12,900,096 ((N+1)*32; fuse1->fuse2) end 16,100,128
    //  ZERO REGION (single memset): bcnt8 @16,100,128 (6,256),
    //    ovcnt @16,106,384 (1), pad, ov @16,106,386 (2*OVCAP=32,512)
    int* ws       = (int*)d_ws;
    int* cnt      = ws;
    int* col64    = ws + 100032;
    unsigned* xph = (unsigned*)(ws + 6500032);
    unsigned* ebuf= (unsigned*)(ws + 7300064);
    __half* wl2h  = (__half*)(ws + 12200000);
    __half* wr2h  = (__half*)(ws + 12202048);
    unsigned* h1h = (unsigned*)(ws + 12900096);
    int* bcnt8    = ws + 16100128;
    int* ovcnt    = ws + 16106384;
    int* ov       = ws + 16106386;

    int csz = (E + NBLK - 1) / NBLK;                  // 6250
    int nprep = ((N + 1) * 8 + 255) / 256;            // 3126
    int zcount = 6256 + 2 + 2 * OVCAP;                // bcnt8+ovcnt+pad+ov

    hipMemsetAsync(bcnt8, 0, (size_t)zcount * sizeof(int), stream);

    k_pb    <<<NBLK + nprep, 256, 0, stream>>>(x, Wl2, Wr2, srcp, dstp, xph,
                                               wl2h, wr2h, ebuf, bcnt8,
                                               ovcnt, ov, E, csz, N);
    k_fuse1 <<<NBKT, 512, 0, stream>>>(ebuf, bcnt8, x, xph, Wl1, bl1, Wr1,
                                       cnt, col64, ovcnt, ov, h1h, N);
    k_fuse2 <<<(N + NB2 - 1) / NB2, 256, 0, stream>>>((const uint4*)h1h, col64,
                                       cnt, ovcnt, ov,
                                       wl2h, wr2h, bl2, Wlin, blin, out, N);
}

// Round 19
// 235.098 us; speedup vs baseline: 1.1032x; 1.0171x over previous
//
#include <hip/hip_runtime.h>
#include <hip/hip_fp16.h>

#define IN_CH 11
#define HID 64
#define PAD 64
#define OVCAP 16256
#define NBLK 512
#define BSH 7            // bucket = dst >> 7 (128 nodes/bucket)
#define NBKT 782         // ceil(100000/128)
#define CAP8 768         // per-(xcd,bucket) capacity: mean 512, +11 sigma
#define OVFLAG (1 << 30) // marks cell-overflow ov entries (written by build role)
#define NB2 32           // fuse2 nodes per block (grid 3125 -> fills the CUs)

typedef _Float16 half8_t __attribute__((ext_vector_type(8)));
typedef float f32x4_t __attribute__((ext_vector_type(4)));
typedef int i32x4_t __attribute__((ext_vector_type(4)));

// ---- k_pb: build role (blocks 0..NBLK-1) + prep role (rest).
__global__ __launch_bounds__(256) void k_pb(
        const float* __restrict__ x, const float* __restrict__ Wl2,
        const float* __restrict__ Wr2, const int* __restrict__ src,
        const int* __restrict__ dst, unsigned* __restrict__ xphu,
        __half* __restrict__ wl2h, __half* __restrict__ wr2h,
        unsigned* __restrict__ ebuf, int* __restrict__ bcnt8,
        int* __restrict__ ovcnt, int* __restrict__ ov,
        int E, int csz, int N) {
    __shared__ int h[NBKT];
    __shared__ int cur[NBKT];
    __shared__ int lim[NBKT];
    int tid = threadIdx.x, blk = blockIdx.x;
    if (blk >= NBLK) {
        // ---- prep role ----
        int i = (blk - NBLK) * 256 + tid;
        if (i < HID * HID) {
            wl2h[i] = __float2half_rn(Wl2[i]);
            wr2h[i] = __float2half_rn(Wr2[i]);
        }
        if (i < (N + 1) * 8) {               // one uint = 2 fp16 channels
            int n = i >> 3, j = (i & 7) * 2;
            float a = 0.f, b = 0.f;
            if (n < N) {
                if (j < IN_CH) a = x[n * IN_CH + j];
                if (j + 1 < IN_CH) b = x[n * IN_CH + j + 1];
            }
            unsigned lo = (unsigned)__half_as_ushort(__float2half_rn(a));
            unsigned hi = (unsigned)__half_as_ushort(__float2half_rn(b));
            xphu[i] = lo | (hi << 16);
        }
        return;
    }
    // ---- build role ----
    int xcd = blk & 7;
    for (int t = tid; t < NBKT; t += 256) h[t] = 0;
    __syncthreads();
    int c0 = blk * csz, c1 = min(c0 + csz, E);
    for (int base = c0; base < c1; base += 1024) {
        int d[4]; bool ok[4];
        #pragma unroll
        for (int k = 0; k < 4; k++) {
            int e = base + tid + k * 256;
            ok[k] = e < c1;
            d[k] = ok[k] ? dst[e] : 0;
        }
        #pragma unroll
        for (int k = 0; k < 4; k++)
            if (ok[k]) atomicAdd(&h[d[k] >> BSH], 1);
    }
    __syncthreads();
    for (int t = tid; t < NBKT; t += 256) {
        int hc = h[t];
        int cell = xcd * NBKT + t;
        int base = cell * CAP8;
        int off = (hc > 0) ? atomicAdd(&bcnt8[cell], hc) : 0;
        cur[t] = base + off;
        lim[t] = base + CAP8;
    }
    __syncthreads();
    for (int base = c0; base < c1; base += 1024) {
        int d[4], s[4], slot[4];
        bool ok[4];
        #pragma unroll
        for (int k = 0; k < 4; k++) {
            int e = base + tid + k * 256;
            ok[k] = e < c1;
            d[k] = ok[k] ? dst[e] : 0;
            s[k] = ok[k] ? __builtin_nontemporal_load(&src[e]) : 0;
        }
        #pragma unroll
        for (int k = 0; k < 4; k++)
            if (ok[k]) slot[k] = atomicAdd(&cur[d[k] >> BSH], 1);
        #pragma unroll
        for (int k = 0; k < 4; k++) {
            if (!ok[k]) continue;
            if (slot[k] < lim[d[k] >> BSH]) {
                ebuf[slot[k]] = ((unsigned)s[k] << 7) | (unsigned)(d[k] & 127);
            } else {
                int q = atomicAdd(ovcnt, 1);
                if (q < OVCAP) { ov[2 * q] = d[k] | OVFLAG; ov[2 * q + 1] = s[k]; }
            }
        }
    }
}

// ---- fuse1 = bbuild + agg1 + ov1 + dense1: col image in LDS (rotated rows to
// kill write bank conflicts), layer-1 aggregate from LDS, dense -> h1h.
// launch_bounds(512,8): VGPR cap 64 (was 32-squeezed) -> deeper gather pipeline
// while keeping 8 waves/SIMD (LDS caps at 4 blocks/CU anyway).
__global__ __launch_bounds__(512, 8) void k_fuse1(
    const unsigned* __restrict__ ebuf, const int* __restrict__ bcnt8,
    const float* __restrict__ x, const unsigned* __restrict__ xphu,
    const float* __restrict__ Wl, const float* __restrict__ bl,
    const float* __restrict__ Wr,
    int* __restrict__ cnt, int* __restrict__ col64,
    int* __restrict__ ovcnt, int* __restrict__ ov,
    unsigned* __restrict__ h1h, int N) {
    __shared__ int lc[128];
    __shared__ int colsh[128 * PAD];     // 32 KB
    __shared__ float aggsh[128][12];     // 6 KB (IN_CH=11 real channels + 1)
    int tid = threadIdx.x, b = blockIdx.x;
    int lo = b << BSH, hi = min(lo + 128, N);
    int nn = hi - lo;
    for (int i = tid; i < 128 * PAD / 4; i += 512) {
        i32x4_t fill = {N, N, N, N};
        ((i32x4_t*)colsh)[i] = fill;
    }
    if (tid < 128) lc[tid] = 0;
    for (int i = tid; i < 128 * 12; i += 512) ((float*)aggsh)[i] = 0.f;
    __syncthreads();
    // build col image: flat loop over all 8 segments, prefetched bounds -> MLP
    int ccs[8];
    #pragma unroll
    for (int xc = 0; xc < 8; xc++)
        ccs[xc] = min(bcnt8[xc * NBKT + b], CAP8);
    for (int i = tid; i < 8 * CAP8; i += 512) {
        int xc = i / CAP8;
        int idx = i - xc * CAP8;
        if (idx < ccs[xc]) {
            unsigned p = __builtin_nontemporal_load(
                &ebuf[(size_t)(xc * NBKT + b) * CAP8 + idx]);
            int row = (int)(p & 127u);
            int sv  = (int)(p >> 7);
            int r = atomicAdd(&lc[row], 1);
            if (r < PAD) {
                colsh[(row << 6) | ((r + row) & 63)] = sv;   // rotated slot
            } else {
                int q = atomicAdd(ovcnt, 1);
                if (q < OVCAP) { ov[2 * q] = lo + row; ov[2 * q + 1] = sv; }
                for (int ch = 0; ch < IN_CH; ch++)           // layer-1 inline
                    atomicAdd(&aggsh[row][ch], x[sv * IN_CH + ch]);
            }
        }
    }
    __syncthreads();
    // cell-overflow entries (flagged, written by build role, complete) layer 1
    {
        int c = *ovcnt; if (c > OVCAP) c = OVCAP;
        for (int i = tid; i < c; i += 512) {
            int d = ov[2 * i];
            if (d & OVFLAG) {
                int dd = d & ~OVFLAG;
                if (dd >= lo && dd < hi) {
                    int s = ov[2 * i + 1];
                    for (int ch = 0; ch < IN_CH; ch++)
                        atomicAdd(&aggsh[dd - lo][ch], x[s * IN_CH + ch]);
                }
            }
        }
    }
    // col64 + cnt writeout (regular stores: fuse2 reads benefit from L2)
    {
        i32x4_t* dst4 = (i32x4_t*)col64 + (size_t)lo * 16;
        for (int i = tid; i < nn * 16; i += 512) dst4[i] = ((i32x4_t*)colsh)[i];
        if (tid < nn) cnt[lo + tid] = lc[tid];
        if (b == 0 && tid < 32) h1h[(size_t)N * 32 + tid] = 0u;   // pad row
    }
    __syncthreads();
    // agg1 phase: 2 rows per iteration for MLP; reads all 64 slots per row
    int lane = tid & 63, wv = tid >> 6;
    int c8 = lane & 7, sub = lane >> 3;
    for (int it = 0; it < 16; it += 2) {
        int rA = wv * 16 + it, rB = rA + 1;
        bool okA = rA < nn, okB = rB < nn;
        int sA[8], sB[8];
        #pragma unroll
        for (int jj = 0; jj < 8; jj++) {
            sA[jj] = okA ? colsh[(rA << 6) | (sub + 8 * jj)] : N;
            sB[jj] = okB ? colsh[(rB << 6) | (sub + 8 * jj)] : N;
        }
        unsigned vA[8], vB[8];
        #pragma unroll
        for (int jj = 0; jj < 8; jj++) vA[jj] = xphu[sA[jj] * 8 + c8];
        #pragma unroll
        for (int jj = 0; jj < 8; jj++) vB[jj] = xphu[sB[jj] * 8 + c8];
        __half2 aA = __floats2half2_rn(0.f, 0.f);
        __half2 aB = __floats2half2_rn(0.f, 0.f);
        #pragma unroll
        for (int jj = 0; jj < 8; jj++) {
            aA = __hadd2(aA, *(__half2*)&vA[jj]);
            aB = __hadd2(aB, *(__half2*)&vB[jj]);
        }
        float2 fA = __half22float2(aA);
        float2 fB = __half22float2(aB);
        #pragma unroll
        for (int off = 8; off <= 32; off <<= 1) {
            fA.x += __shfl_xor(fA.x, off);
            fA.y += __shfl_xor(fA.y, off);
            fB.x += __shfl_xor(fB.x, off);
            fB.y += __shfl_xor(fB.y, off);
        }
        // channels 2*lane, 2*lane+1; only lanes 0-5 carry real channels (0-11)
        if (lane < 6 && okA) {
            aggsh[rA][2 * lane]     += fA.x;
            aggsh[rA][2 * lane + 1] += fA.y;
        }
        if (lane < 6 && okB) {
            aggsh[rB][2 * lane]     += fB.x;
            aggsh[rB][2 * lane + 1] += fB.y;
        }
    }
    __syncthreads();
    // dense1 phase: 2 rows per iteration
    for (int it = 0; it < 16; it += 2) {
        int rA = wv * 16 + it, rB = rA + 1;
        bool okA = rA < nn, okB = rB < nn;
        int nA = lo + (okA ? rA : 0), nB = lo + (okB ? rB : 0);
        int degA = okA ? lc[rA] : 0, degB = okB ? lc[rB] : 0;
        float invA = degA > 0 ? 1.f / (float)degA : 0.f;
        float invB = degB > 0 ? 1.f / (float)degB : 0.f;
        float mvA = (okA && lane < 12) ? aggsh[rA][lane] * invA : 0.f;
        float mvB = (okB && lane < 12) ? aggsh[rB][lane] * invB : 0.f;
        float xvA = (lane < IN_CH) ? x[nA * IN_CH + lane] : 0.f;
        float xvB = (lane < IN_CH) ? x[nB * IN_CH + lane] : 0.f;
        float hA = bl[lane], hB = hA;
        #pragma unroll
        for (int c = 0; c < IN_CH; c++) {
            float wl = Wl[lane * IN_CH + c], wr = Wr[lane * IN_CH + c];
            hA += wl * __shfl(mvA, c) + wr * __shfl(xvA, c);
            hB += wl * __shfl(mvB, c) + wr * __shfl(xvB, c);
        }
        hA = fmaxf(hA, 0.f); hB = fmaxf(hB, 0.f);
        unsigned myA = (unsigned)__half_as_ushort(__float2half_rn(hA));
        unsigned myB = (unsigned)__half_as_ushort(__float2half_rn(hB));
        unsigned nxA = __shfl_down(myA, 1);
        unsigned nxB = __shfl_down(myB, 1);
        if ((lane & 1) == 0) {
            if (okA) h1h[nA * 32 + (lane >> 1)] = myA | (nxA << 16);
            if (okB) h1h[nB * 32 + (lane >> 1)] = myB | (nxB << 16);
        }
    }
}

// ---- fuse2 = agg2 + ov2 + dense2: 32 nodes/block, 256 threads.
// launch_bounds(256,4): VGPR cap 128 (was 52-squeezed) -> the 2-row x 8-load
// gather batch stays fully in flight (latency-bound phase).
__global__ __launch_bounds__(256, 4) void k_fuse2(
    const uint4* __restrict__ h1h4, const int* __restrict__ col64,
    const int* __restrict__ cnt, const int* __restrict__ ovcnt,
    const int* __restrict__ ov,
    const __half* __restrict__ wl2h, const __half* __restrict__ wr2h,
    const float* __restrict__ bl, const float* __restrict__ Wlin,
    const float* __restrict__ blin, float* __restrict__ out, int N) {
    union U { uint4 u; half8_t h; };
    __shared__ uint4 meansh[NB2 * 8];    // 4 KB fp16 means, XOR-swizzled
    __shared__ uint4 wsh[2][64 * 8];     // 16 KB weights, XOR-swizzled
    int tid = threadIdx.x, b = blockIdx.x;
    int lo = b * NB2, hi = min(lo + NB2, N);
    int nn = hi - lo;
    int lane = tid & 63, wv = tid >> 6;  // 4 waves
    // stage weights (L2-hot) into LDS; swizzle pos q^(o&7)
    {
        const uint4* wlu = (const uint4*)wl2h;
        const uint4* wru = (const uint4*)wr2h;
        for (int i = tid; i < 64 * 8; i += 256) {
            int o = i >> 3, q = i & 7;
            wsh[0][(o << 3) | (q ^ (o & 7))] = wlu[i];
            wsh[1][(o << 3) | (q ^ (o & 7))] = wru[i];
        }
    }
    // phase A: per-node gather + fp16 mean -> LDS, 2 rows per iteration,
    // 8 rows per wave.
    int c8 = lane & 7, sub = lane >> 3;
    for (int it = 0; it < 8; it += 2) {
        int rA = wv * 8 + it, rB = rA + 1;
        bool okA = rA < nn, okB = rB < nn;
        int nA = lo + (okA ? rA : 0), nB = lo + (okB ? rB : 0);
        const int* cbA = col64 + (size_t)nA * PAD;
        const int* cbB = col64 + (size_t)nB * PAD;
        int sA[8], sB[8];
        #pragma unroll
        for (int jj = 0; jj < 8; jj++) {
            sA[jj] = okA ? __builtin_nontemporal_load(&cbA[sub + 8 * jj]) : N;
            sB[jj] = okB ? __builtin_nontemporal_load(&cbB[sub + 8 * jj]) : N;
        }
        uint4 vA[8], vB[8];
        #pragma unroll
        for (int jj = 0; jj < 8; jj++) vA[jj] = h1h4[(size_t)sA[jj] * 8 + c8];
        #pragma unroll
        for (int jj = 0; jj < 8; jj++) vB[jj] = h1h4[(size_t)sB[jj] * 8 + c8];
        __half2 aA[4], aB[4];
        #pragma unroll
        for (int t = 0; t < 4; t++) {
            aA[t] = __floats2half2_rn(0.f, 0.f);
            aB[t] = __floats2half2_rn(0.f, 0.f);
        }
        #pragma unroll
        for (int jj = 0; jj < 8; jj++) {
            aA[0] = __hadd2(aA[0], *(__half2*)&vA[jj].x);
            aA[1] = __hadd2(aA[1], *(__half2*)&vA[jj].y);
            aA[2] = __hadd2(aA[2], *(__half2*)&vA[jj].z);
            aA[3] = __hadd2(aA[3], *(__half2*)&vA[jj].w);
            aB[0] = __hadd2(aB[0], *(__half2*)&vB[jj].x);
            aB[1] = __hadd2(aB[1], *(__half2*)&vB[jj].y);
            aB[2] = __hadd2(aB[2], *(__half2*)&vB[jj].z);
            aB[3] = __hadd2(aB[3], *(__half2*)&vB[jj].w);
        }
        float accA[8], accB[8];
        #pragma unroll
        for (int t = 0; t < 4; t++) {
            float2 fA = __half22float2(aA[t]);
            float2 fB = __half22float2(aB[t]);
            accA[2 * t] = fA.x; accA[2 * t + 1] = fA.y;
            accB[2 * t] = fB.x; accB[2 * t + 1] = fB.y;
        }
        #pragma unroll
        for (int off = 8; off <= 32; off <<= 1) {
            #pragma unroll
            for (int t = 0; t < 8; t++) {
                accA[t] += __shfl_xor(accA[t], off);
                accB[t] += __shfl_xor(accB[t], off);
            }
        }
        if (sub == 0) {
            if (okA) {
                int deg = cnt[nA];
                float inv = deg > 0 ? 1.f / (float)deg : 0.f;
                __half2 h0 = __floats2half2_rn(accA[0] * inv, accA[1] * inv);
                __half2 h1 = __floats2half2_rn(accA[2] * inv, accA[3] * inv);
                __half2 h2 = __floats2half2_rn(accA[4] * inv, accA[5] * inv);
                __half2 h3 = __floats2half2_rn(accA[6] * inv, accA[7] * inv);
                uint4 o;
                o.x = *(unsigned*)&h0; o.y = *(unsigned*)&h1;
                o.z = *(unsigned*)&h2; o.w = *(unsigned*)&h3;
                meansh[(rA << 3) | (c8 ^ (rA & 7))] = o;
            }
            if (okB) {
                int deg = cnt[nB];
                float inv = deg > 0 ? 1.f / (float)deg : 0.f;
                __half2 h0 = __floats2half2_rn(accB[0] * inv, accB[1] * inv);
                __half2 h1 = __floats2half2_rn(accB[2] * inv, accB[3] * inv);
                __half2 h2 = __floats2half2_rn(accB[4] * inv, accB[5] * inv);
                __half2 h3 = __floats2half2_rn(accB[6] * inv, accB[7] * inv);
                uint4 o;
                o.x = *(unsigned*)&h0; o.y = *(unsigned*)&h1;
                o.z = *(unsigned*)&h2; o.w = *(unsigned*)&h3;
                meansh[(rB << 3) | (c8 ^ (rB & 7))] = o;
            }
        }
    }
    __syncthreads();
    // phase B: overflow contributions (statistically empty; serial is fine)
    if (tid == 0) {
        int c = *ovcnt; if (c > OVCAP) c = OVCAP;
        for (int i = 0; i < c; i++) {
            int d = ov[2 * i] & ~OVFLAG;
            if (d >= lo && d < hi && (ov[2 * i] != 0)) {
                int s = ov[2 * i + 1];
                int row = d - lo;
                int deg = cnt[d];
                float inv = deg > 0 ? 1.f / (float)deg : 0.f;
                for (int q = 0; q < 8; q++) {
                    uint4* mp = &meansh[(row << 3) | (q ^ (row & 7))];
                    uint4 m = *mp;
                    uint4 hh = h1h4[(size_t)s * 8 + q];
                    __half2* m2 = (__half2*)&m;
                    __half2* h2v = (__half2*)&hh;
                    for (int k = 0; k < 4; k++) {
                        float2 fm = __half22float2(m2[k]);
                        float2 fh = __half22float2(h2v[k]);
                        m2[k] = __floats2half2_rn(fm.x + fh.x * inv, fm.y + fh.y * inv);
                    }
                    *mp = m;
                }
            }
        }
    }
    __syncthreads();
    // phase C: dense2 MFMA; waves 0,1 each handle one 16-node tile
    int r16 = lane & 15, quad = lane >> 4;
    int rb = wv * 16;
    if (wv < 2 && rb < nn) {
        float bl_c[4], wl_c[4];
        #pragma unroll
        for (int tt = 0; tt < 4; tt++) {
            bl_c[tt] = bl[tt * 16 + r16];
            wl_c[tt] = Wlin[tt * 16 + r16];
        }
        float b0 = blin[0];
        int row = rb + r16; if (row >= nn) row = nn - 1;
        int n = lo + row;
        U a0, a1, a2, a3;
        a0.u = meansh[(row << 3) | (quad ^ (row & 7))];
        a1.u = meansh[(row << 3) | ((4 + quad) ^ (row & 7))];
        a2.u = h1h4[(size_t)n * 8 + quad];
        a3.u = h1h4[(size_t)n * 8 + 4 + quad];
        float p0 = 0.f, p1 = 0.f, p2 = 0.f, p3 = 0.f;
        #pragma unroll
        for (int tt = 0; tt < 4; tt++) {
            int o = tt * 16 + r16;
            U b0u, b1u, b2u, b3u;
            b0u.u = wsh[0][(o << 3) | (quad ^ (o & 7))];
            b1u.u = wsh[0][(o << 3) | ((4 + quad) ^ (o & 7))];
            b2u.u = wsh[1][(o << 3) | (quad ^ (o & 7))];
            b3u.u = wsh[1][(o << 3) | ((4 + quad) ^ (o & 7))];
            f32x4_t c = {0.f, 0.f, 0.f, 0.f};
            c = __builtin_amdgcn_mfma_f32_16x16x32_f16(a0.h, b0u.h, c, 0, 0, 0);
            c = __builtin_amdgcn_mfma_f32_16x16x32_f16(a1.h, b1u.h, c, 0, 0, 0);
            c = __builtin_amdgcn_mfma_f32_16x16x32_f16(a2.h, b2u.h, c, 0, 0, 0);
            c = __builtin_amdgcn_mfma_f32_16x16x32_f16(a3.h, b3u.h, c, 0, 0, 0);
            p0 += fmaxf(c[0] + bl_c[tt], 0.f) * wl_c[tt];
            p1 += fmaxf(c[1] + bl_c[tt], 0.f) * wl_c[tt];
            p2 += fmaxf(c[2] + bl_c[tt], 0.f) * wl_c[tt];
            p3 += fmaxf(c[3] + bl_c[tt], 0.f) * wl_c[tt];
        }
        #pragma unroll
        for (int off = 1; off <= 8; off <<= 1) {
            p0 += __shfl_xor(p0, off); p1 += __shfl_xor(p1, off);
            p2 += __shfl_xor(p2, off); p3 += __shfl_xor(p3, off);
        }
        if (r16 == 0) {
            int nn2 = lo + rb + quad * 4;
            if (nn2 + 3 < N) {
                ((float4*)out)[nn2 >> 2] = make_float4(p0 + b0, p1 + b0, p2 + b0, p3 + b0);
            } else {
                if (nn2 + 0 < N) out[nn2 + 0] = p0 + b0;
                if (nn2 + 1 < N) out[nn2 + 1] = p1 + b0;
                if (nn2 + 2 < N) out[nn2 + 2] = p2 + b0;
                if (nn2 + 3 < N) out[nn2 + 3] = p3 + b0;
            }
        }
    }
}

// ---------------- launch ----------------

extern "C" void kernel_launch(void* const* d_in, const int* in_sizes, int n_in,
                              void* d_out, int out_size, void* d_ws, size_t ws_size,
                              hipStream_t stream) {
    const float* x    = (const float*)d_in[0];
    const int*   ei   = (const int*)d_in[1];
    const float* Wl1  = (const float*)d_in[2];
    const float* bl1  = (const float*)d_in[3];
    const float* Wr1  = (const float*)d_in[4];
    const float* Wl2  = (const float*)d_in[5];
    const float* bl2  = (const float*)d_in[6];
    const float* Wr2  = (const float*)d_in[7];
    const float* Wlin = (const float*)d_in[8];
    const float* blin = (const float*)d_in[9];
    float* out = (float*)d_out;

    int N = in_sizes[0] / IN_CH;   // 100000
    int E = in_sizes[1] / 2;       // 3200000
    const int* srcp = ei;
    const int* dstp = ei + E;

    // workspace (int offsets; max use 16,138,898 ints < 16,139,040 budget):
    //  cnt   @ 0          (N)
    //  col64 @ 100,032    (6.4M; fuse1->fuse2)
    //  xph   @ 6,500,032  ((N+1)*8; pb->fuse1)
    //  ebuf  @ 7,300,064  (8*782*768 = 4,804,608; pb->fuse1) end 12,104,672
    //  wl2h  @ 12,200,000 (2048 ints = 4096 halfs)
    //  wr2h  @ 12,202,048 (2048 ints)  [end 12,204,096 < h1h start]
    //  h1h   @ 12,900,096 ((N+1)*32; fuse1->fuse2) end 16,100,128
    //  ZERO REGION (single memset): bcnt8 @16,100,128 (6,256),
    //    ovcnt @16,106,384 (1), pad, ov @16,106,386 (2*OVCAP=32,512)
    int* ws       = (int*)d_ws;
    int* cnt      = ws;
    int* col64    = ws + 100032;
    unsigned* xph = (unsigned*)(ws + 6500032);
    unsigned* ebuf= (unsigned*)(ws + 7300064);
    __half* wl2h  = (__half*)(ws + 12200000);
    __half* wr2h  = (__half*)(ws + 12202048);
    unsigned* h1h = (unsigned*)(ws + 12900096);
    int* bcnt8    = ws + 16100128;
    int* ovcnt    = ws + 16106384;
    int* ov       = ws + 16106386;

    int csz = (E + NBLK - 1) / NBLK;                  // 6250
    int nprep = ((N + 1) * 8 + 255) / 256;            // 3126
    int zcount = 6256 + 2 + 2 * OVCAP;                // bcnt8+ovcnt+pad+ov

    hipMemsetAsync(bcnt8, 0, (size_t)zcount * sizeof(int), stream);

    k_pb    <<<NBLK + nprep, 256, 0, stream>>>(x, Wl2, Wr2, srcp, dstp, xph,
                                               wl2h, wr2h, ebuf, bcnt8,
                                               ovcnt, ov, E, csz, N);
    k_fuse1 <<<NBKT, 512, 0, stream>>>(ebuf, bcnt8, x, xph, Wl1, bl1, Wr1,
                                       cnt, col64, ovcnt, ov, h1h, N);
    k_fuse2 <<<(N + NB2 - 1) / NB2, 256, 0, stream>>>((const uint4*)h1h, col64,
                                       cnt, ovcnt, ov,
                                       wl2h, wr2h, bl2, Wlin, blin, out, N);
}